// Round 5
// baseline (4061.600 us; speedup 1.0000x reference)
//
#include <hip/hip_runtime.h>
#include <hip/hip_bf16.h>

#define TLEN 4096
#define HPADT 512
#define SQRT_HALF 0.70710678118654752f

typedef __attribute__((ext_vector_type(8))) short short8;
typedef __attribute__((ext_vector_type(4))) float floatx4;
typedef __attribute__((ext_vector_type(4))) unsigned short ushort4v;

#define MFMA_BF16(a, b, c) __builtin_amdgcn_mfma_f32_16x16x32_bf16((a), (b), (c), 0, 0, 0)

__device__ __forceinline__ float bf2f(unsigned short u) {
  union { unsigned int i; float f; } v; v.i = ((unsigned int)u) << 16; return v.f;
}
__device__ __forceinline__ unsigned short f2bf(float x) {
  union { float f; unsigned int i; } v; v.f = x;
  unsigned int r = v.i + 0x7FFFu + ((v.i >> 16) & 1u);
  return (unsigned short)(r >> 16);
}
__device__ __forceinline__ short8 ld8(const unsigned short* p) { return *(const short8*)p; }

// Stage NI*256 16B chunks of a [rows][128-elem] bf16 tile into LDS, XOR-swizzled:
// data chunk c of row r lands at slot (c ^ (r&15)). dest = wave-uniform base + lane*16.
template <int NI>
__device__ __forceinline__ void stage128(unsigned short* lds, const unsigned short* src,
                                         int stride, int tid) {
  #pragma unroll
  for (int inst = 0; inst < NI; ++inst) {
    int qb = inst * 256 + (tid & 192);
    int q = qb + (tid & 63);
    int r = q >> 4;
    int c = (q & 15) ^ (r & 15);
    __builtin_amdgcn_global_load_lds(
        (const __attribute__((address_space(1))) unsigned int*)(src + (size_t)r * stride + (c << 3)),
        (__attribute__((address_space(3))) unsigned int*)(lds + qb * 8),
        16, 0, 0);
  }
}

__device__ __forceinline__ short8 frag128(const unsigned short* lds, int r, int cj) {
  return *(const short8*)(lds + r * 128 + ((cj ^ (r & 15)) << 3));
}

// monotonic grid barrier: all 256 blocks co-resident (1 block/CU)
__device__ __forceinline__ void grid_barrier(int* bar, int target) {
  __threadfence();
  __syncthreads();
  if (threadIdx.x == 0) {
    atomicAdd(bar, 1);
    while (__hip_atomic_load(bar, __ATOMIC_RELAXED, __HIP_MEMORY_SCOPE_AGENT) < target)
      __builtin_amdgcn_s_sleep(2);
  }
  __syncthreads();
  __threadfence();
}

// ============ merged weight pre-cast (once per call) ============
__global__ __launch_bounds__(256) void cast_all_kernel(
    const float* __restrict__ fw, const float* __restrict__ gw,
    const float* __restrict__ rw, const float* __restrict__ sw,
    const float* __restrict__ cf, const float* __restrict__ cg,
    const float* __restrict__ f1, const float* __restrict__ fb,
    const float* __restrict__ cfb, const float* __restrict__ gb,
    const float* __restrict__ cgb,
    unsigned short* __restrict__ WA, unsigned short* __restrict__ RS,
    unsigned short* __restrict__ CA, unsigned short* __restrict__ F1c,
    float* __restrict__ fgb)
{
  int b = blockIdx.x;
  if (b < 7680) {
    size_t idx = (size_t)b * 256 + threadIdx.x;
    size_t l = idx >> 16;
    int o = (int)((idx >> 7) & 511);
    int i4 = (int)(idx & 127) * 4;
    const float4* fp = (const float4*)(fw + (((l * 512 + o) * 512 + i4) * 2));
    const float4* gp = (const float4*)(gw + (((l * 512 + o) * 512 + i4) * 2));
    float4 f0 = fp[0], f1v = fp[1];
    float4 g0 = gp[0], g1 = gp[1];
    size_t base0 = ((l * 2 + 0) * 1024);
    size_t base1 = ((l * 2 + 1) * 1024);
    *(ushort4v*)&WA[(base0 + o) * 512 + i4]       = (ushort4v){f2bf(f0.x), f2bf(f0.z), f2bf(f1v.x), f2bf(f1v.z)};
    *(ushort4v*)&WA[(base1 + o) * 512 + i4]       = (ushort4v){f2bf(f0.y), f2bf(f0.w), f2bf(f1v.y), f2bf(f1v.w)};
    *(ushort4v*)&WA[(base0 + 512 + o) * 512 + i4] = (ushort4v){f2bf(g0.x), f2bf(g0.z), f2bf(g1.x), f2bf(g1.z)};
    *(ushort4v*)&WA[(base1 + 512 + o) * 512 + i4] = (ushort4v){f2bf(g0.y), f2bf(g0.w), f2bf(g1.y), f2bf(g1.w)};
  } else if (b < 15360) {
    size_t idx = (size_t)(b - 7680) * 256 + threadIdx.x;
    size_t l = idx >> 16;
    int o = (int)((idx >> 7) & 511);
    int i4 = (int)(idx & 127) * 4;
    float4 r4 = *(const float4*)(rw + ((l * 512 + o) * 512 + i4));
    float4 s4 = *(const float4*)(sw + ((l * 512 + o) * 512 + i4));
    *(ushort4v*)&RS[(l * 1024 + o) * 512 + i4]       = (ushort4v){f2bf(r4.x), f2bf(r4.y), f2bf(r4.z), f2bf(r4.w)};
    *(ushort4v*)&RS[(l * 1024 + 512 + o) * 512 + i4] = (ushort4v){f2bf(s4.x), f2bf(s4.y), f2bf(s4.z), f2bf(s4.w)};
  } else if (b < 17280) {
    size_t idx = (size_t)(b - 15360) * 256 + threadIdx.x;
    size_t l = idx >> 14;
    int o = (int)((idx >> 5) & 511);
    int i4 = (int)(idx & 31) * 4;
    float4 f4 = *(const float4*)(cf + ((l * 512 + o) * 128 + i4));
    float4 g4 = *(const float4*)(cg + ((l * 512 + o) * 128 + i4));
    *(ushort4v*)&CA[(l * 1024 + o) * 128 + i4]       = (ushort4v){f2bf(f4.x), f2bf(f4.y), f2bf(f4.z), f2bf(f4.w)};
    *(ushort4v*)&CA[(l * 1024 + 512 + o) * 128 + i4] = (ushort4v){f2bf(g4.x), f2bf(g4.y), f2bf(g4.z), f2bf(g4.w)};
  } else if (b < 17536) {
    size_t idx = (size_t)(b - 17280) * 256 + threadIdx.x;
    float4 v = *(const float4*)(f1 + idx * 4);
    *(ushort4v*)&F1c[idx * 4] = (ushort4v){f2bf(v.x), f2bf(v.y), f2bf(v.z), f2bf(v.w)};
  } else {
    int idx = (b - 17536) * 256 + threadIdx.x;
    int l = idx >> 10, r = idx & 1023;
    float v;
    if (r < 512) v = fb[l * 512 + r] + cfb[l * 512 + r];
    else         v = gb[l * 512 + r - 512] + cgb[l * 512 + r - 512];
    fgb[idx] = v;
  }
}

// ============ upsample ============

__global__ __launch_bounds__(256) void upsample1_kernel(
    const float* __restrict__ c, const float* __restrict__ up_w,
    const float* __restrict__ up_b, float* __restrict__ u1)
{
  int x = threadIdx.x;
  int h = blockIdx.x;
  const float* w = up_w;
  float acc = 0.f;
  int k1 = (23 - x) & 15;
  #pragma unroll
  for (int dk = 0; dk < 2; ++dk) {
    int kx = k1 + 16 * dk;
    int num = x + kx - 23;
    if (num >= 0) {
      int qq = num >> 4;
      if (qq < 16) {
        #pragma unroll
        for (int ky = 0; ky < 3; ++ky) {
          int hh = h + ky - 1;
          if (hh >= 0 && hh < 128)
            acc += c[hh * 16 + qq] * w[(2 - ky) * 32 + (31 - kx)];
        }
      }
    }
  }
  acc += up_b[0];
  u1[h * 256 + x] = acc > 0.f ? acc : 0.4f * acc;
}

__global__ __launch_bounds__(256) void upsample2_kernel(
    const float* __restrict__ u1, const float* __restrict__ up_w,
    const float* __restrict__ up_b, unsigned short* __restrict__ cu)
{
  int x = blockIdx.x * 256 + threadIdx.x;
  int h = blockIdx.y;
  const float* w = up_w + 96;
  float acc = 0.f;
  int k1 = (23 - x) & 15;
  #pragma unroll
  for (int dk = 0; dk < 2; ++dk) {
    int kx = k1 + 16 * dk;
    int num = x + kx - 23;
    if (num >= 0) {
      int qq = num >> 4;
      if (qq < 256) {
        #pragma unroll
        for (int ky = 0; ky < 3; ++ky) {
          int hh = h + ky - 1;
          if (hh >= 0 && hh < 128)
            acc += u1[hh * 256 + qq] * w[(2 - ky) * 32 + (31 - kx)];
        }
      }
    }
  }
  acc += up_b[1];
  acc = acc > 0.f ? acc : 0.4f * acc;
  cu[(size_t)x * 128 + h] = f2bf(acc);
}

// ============ front conv -> hf[t][512] fp32, hbf padded bf16 ============
__global__ __launch_bounds__(256) void front_kernel(
    const float* __restrict__ x, const float* __restrict__ fw, const float* __restrict__ fb,
    float* __restrict__ hf, unsigned short* __restrict__ hbf)
{
  __shared__ float xs[40];
  int tid = threadIdx.x;
  int o = blockIdx.y * 256 + tid;
  int t0 = blockIdx.x * 8;
  if (tid < 39) {
    int gx = t0 - 31 + tid;
    xs[tid] = (gx >= 0) ? x[gx] : 0.f;
  }
  __syncthreads();
  float w[32];
  #pragma unroll
  for (int k = 0; k < 32; ++k) w[k] = fw[o * 32 + k];
  float b = fb[o];
  #pragma unroll
  for (int j = 0; j < 8; ++j) {
    float acc = b;
    #pragma unroll
    for (int k = 0; k < 32; ++k) acc += w[k] * xs[j + k];
    acc = acc > 0.f ? acc : 0.f;
    int t = t0 + j;
    hf[(size_t)t * 512 + o] = acc;
    hbf[(size_t)(HPADT + t) * 512 + o] = f2bf(acc);
  }
}

// ============ persistent fused layer kernel ============
// grid = 256 blocks (1/CU). block b: n0 = (b&31)*128 (t-tile), m0 = (b>>5)*64 (oc-tile).
// h (fp32) and skip (fp32) tiles live in registers for all 30 layers.
__global__ __launch_bounds__(256, 1) void wavenet_main_kernel(
    const unsigned short* __restrict__ WA_all,  // [30][2][1024][512]
    const unsigned short* __restrict__ RS_all,  // [30][1024][512]
    const unsigned short* __restrict__ CA_all,  // [30][1024][128]
    const float* __restrict__ fgb_all,          // [30][1024]
    const float* __restrict__ rb_all,           // [30][512]
    const float* __restrict__ sb_all,           // [30][512]
    const unsigned short* __restrict__ cu,      // [T][128]
    const float* __restrict__ hf_init,          // [T][512] fp32
    unsigned short* __restrict__ hbf,           // [(HPADT+T)][512]
    unsigned short* __restrict__ obf,           // [T][512]
    unsigned short* __restrict__ skipbf,        // [T][512]
    int* __restrict__ bar)
{
  __shared__ unsigned short Af[2][64 * 128];
  __shared__ unsigned short Ag[2][64 * 128];
  __shared__ unsigned short Xs[2][128 * 128];

  const int tid = threadIdx.x;
  const int lane = tid & 63;
  const int wave = tid >> 6;
  const int lm = lane & 15, qd = lane >> 4;
  const int n0 = (blockIdx.x & 31) * 128;
  const int m0 = (blockIdx.x >> 5) * 64;
  const int wm = (wave & 1) * 32;
  const int wn = (wave >> 1) * 64;

  // persistent register state: h and skip tiles (fp32), B-epilogue layout
  floatx4 hfr[2][4], skr[2][4];
  #pragma unroll
  for (int mt = 0; mt < 2; ++mt) {
    int oc0 = m0 + wm + mt * 16 + qd * 4;
    #pragma unroll
    for (int nt = 0; nt < 4; ++nt) {
      int t = n0 + wn + nt * 16 + lm;
      hfr[mt][nt] = *(const floatx4*)&hf_init[(size_t)t * 512 + oc0];
      skr[mt][nt] = (floatx4){0.f, 0.f, 0.f, 0.f};
    }
  }

  int bar_t = 0;

  #pragma unroll 1
  for (int l = 0; l < 30; ++l) {
    const int d = 1 << (l % 10);
    const unsigned short* WA = WA_all + (size_t)l * 2 * 524288;
    const unsigned short* CA = CA_all + (size_t)l * 131072;
    const unsigned short* RS = RS_all + (size_t)l * 524288;
    const float* fgbl = fgb_all + l * 1024;
    const float* rbl = rb_all + l * 512;
    const float* sbl = sb_all + l * 512;

    auto stageA_W = [&](int s, int b) {
      if (s < 8) {
        int tap = s >> 2, k0 = (s & 3) * 128;
        const unsigned short* ab = WA + (size_t)tap * 524288;
        stage128<4>(&Af[b][0], ab + (size_t)m0 * 512 + k0, 512, tid);
        stage128<4>(&Ag[b][0], ab + (size_t)(512 + m0) * 512 + k0, 512, tid);
      } else {
        stage128<4>(&Af[b][0], CA + (size_t)m0 * 128, 128, tid);
        stage128<4>(&Ag[b][0], CA + (size_t)(512 + m0) * 128, 128, tid);
      }
    };
    auto stageA_X = [&](int s, int b) {
      if (s < 8) {
        int tap = s >> 2, k0 = (s & 3) * 128;
        stage128<8>(&Xs[b][0], hbf + (size_t)(HPADT + n0 - (tap ? 0 : d)) * 512 + k0, 512, tid);
      } else {
        stage128<8>(&Xs[b][0], cu + (size_t)n0 * 128, 128, tid);
      }
    };
    auto stageB_W = [&](int s, int b) {
      int k0 = s * 128;
      stage128<4>(&Af[b][0], RS + (size_t)m0 * 512 + k0, 512, tid);
      stage128<4>(&Ag[b][0], RS + (size_t)(512 + m0) * 512 + k0, 512, tid);
    };
    auto stageB_X = [&](int s, int b) {
      stage128<8>(&Xs[b][0], obf + (size_t)n0 * 512 + s * 128, 512, tid);
    };

    // ================= phase A: F/G gemm =================
    floatx4 accF[2][4], accG[2][4];
    #pragma unroll
    for (int a = 0; a < 2; ++a)
      #pragma unroll
      for (int b = 0; b < 4; ++b) {
        accF[a][b] = (floatx4){0.f, 0.f, 0.f, 0.f};
        accG[a][b] = (floatx4){0.f, 0.f, 0.f, 0.f};
      }

    stageA_W(0, 0); stageA_X(0, 0);
    for (int s = 0; s < 9; ++s) {
      __syncthreads();
      if (s < 8) { stageA_W(s + 1, (s + 1) & 1); stageA_X(s + 1, (s + 1) & 1); }
      else       { stageB_W(0, 1); }   // prefetch B weights into the free parity buffer
      const unsigned short* af = &Af[s & 1][0];
      const unsigned short* ag = &Ag[s & 1][0];
      const unsigned short* xs = &Xs[s & 1][0];
      #pragma unroll
      for (int j = 0; j < 4; ++j) {
        int cj = j * 4 + qd;
        short8 a[2], g[2], xv[4];
        a[0] = frag128(af, wm + lm, cj);
        a[1] = frag128(af, wm + 16 + lm, cj);
        g[0] = frag128(ag, wm + lm, cj);
        g[1] = frag128(ag, wm + 16 + lm, cj);
        #pragma unroll
        for (int nt = 0; nt < 4; ++nt) xv[nt] = frag128(xs, wn + nt * 16 + lm, cj);
        #pragma unroll
        for (int mt = 0; mt < 2; ++mt)
          #pragma unroll
          for (int nt = 0; nt < 4; ++nt) {
            accF[mt][nt] = MFMA_BF16(a[mt], xv[nt], accF[mt][nt]);
            accG[mt][nt] = MFMA_BF16(g[mt], xv[nt], accG[mt][nt]);
          }
      }
    }

    // epilogue A: o = tanh(f)*sigmoid(g) -> obf
    #pragma unroll
    for (int mt = 0; mt < 2; ++mt) {
      int oc0 = m0 + wm + mt * 16 + qd * 4;
      floatx4 fb4 = *(const floatx4*)&fgbl[oc0];
      floatx4 gb4 = *(const floatx4*)&fgbl[512 + oc0];
      #pragma unroll
      for (int nt = 0; nt < 4; ++nt) {
        int t = n0 + wn + nt * 16 + lm;
        ushort4v o4;
        #pragma unroll
        for (int r = 0; r < 4; ++r) {
          float f = accF[mt][nt][r] + fb4[r];
          float g = accG[mt][nt][r] + gb4[r];
          float ef = __expf(-2.f * f);
          float th = (1.f - ef) / (1.f + ef);
          float sg = 1.f / (1.f + __expf(-g));
          o4[r] = f2bf(th * sg);
        }
        *(ushort4v*)&obf[(size_t)t * 512 + oc0] = o4;
      }
    }

    bar_t += 256;
    grid_barrier(bar, bar_t);

    // ================= phase B: res/skip gemm =================
    floatx4 accR[2][4], accS[2][4];
    #pragma unroll
    for (int a = 0; a < 2; ++a)
      #pragma unroll
      for (int b = 0; b < 4; ++b) {
        accR[a][b] = (floatx4){0.f, 0.f, 0.f, 0.f};
        accS[a][b] = (floatx4){0.f, 0.f, 0.f, 0.f};
      }

    stageB_X(0, 1);   // weights for step 0 already prefetched into buf 1
    for (int s = 0; s < 4; ++s) {
      __syncthreads();
      if (s < 3) { int nb = ((s + 1) & 1) ^ 1; stageB_W(s + 1, nb); stageB_X(s + 1, nb); }
      const int cb = (s & 1) ^ 1;
      const unsigned short* ar = &Af[cb][0];
      const unsigned short* as = &Ag[cb][0];
      const unsigned short* xs = &Xs[cb][0];
      #pragma unroll
      for (int j = 0; j < 4; ++j) {
        int cj = j * 4 + qd;
        short8 a[2], g[2], xv[4];
        a[0] = frag128(ar, wm + lm, cj);
        a[1] = frag128(ar, wm + 16 + lm, cj);
        g[0] = frag128(as, wm + lm, cj);
        g[1] = frag128(as, wm + 16 + lm, cj);
        #pragma unroll
        for (int nt = 0; nt < 4; ++nt) xv[nt] = frag128(xs, wn + nt * 16 + lm, cj);
        #pragma unroll
        for (int mt = 0; mt < 2; ++mt)
          #pragma unroll
          for (int nt = 0; nt < 4; ++nt) {
            accR[mt][nt] = MFMA_BF16(a[mt], xv[nt], accR[mt][nt]);
            accS[mt][nt] = MFMA_BF16(g[mt], xv[nt], accS[mt][nt]);
          }
      }
    }

    // epilogue B: h=(h+res)*sqrt_half (regs), skip+=..., write hbf tile
    #pragma unroll
    for (int mt = 0; mt < 2; ++mt) {
      int oc0 = m0 + wm + mt * 16 + qd * 4;
      floatx4 rb4 = *(const floatx4*)&rbl[oc0];
      floatx4 sb4 = *(const floatx4*)&sbl[oc0];
      #pragma unroll
      for (int nt = 0; nt < 4; ++nt) {
        int t = n0 + wn + nt * 16 + lm;
        ushort4v hb4;
        #pragma unroll
        for (int r = 0; r < 4; ++r) {
          float hv = (hfr[mt][nt][r] + accR[mt][nt][r] + rb4[r]) * SQRT_HALF;
          hfr[mt][nt][r] = hv;
          hb4[r] = f2bf(hv);
          skr[mt][nt][r] += accS[mt][nt][r] + sb4[r];
        }
        *(ushort4v*)&hbf[(size_t)(HPADT + t) * 512 + oc0] = hb4;
      }
    }

    bar_t += 256;
    grid_barrier(bar, bar_t);
  }

  // write relu(skip) as bf16 for final1
  #pragma unroll
  for (int mt = 0; mt < 2; ++mt) {
    int oc0 = m0 + wm + mt * 16 + qd * 4;
    #pragma unroll
    for (int nt = 0; nt < 4; ++nt) {
      int t = n0 + wn + nt * 16 + lm;
      ushort4v sk4;
      #pragma unroll
      for (int r = 0; r < 4; ++r) {
        float v = skr[mt][nt][r];
        sk4[r] = f2bf(v > 0.f ? v : 0.f);
      }
      *(ushort4v*)&skipbf[(size_t)t * 512 + oc0] = sk4;
    }
  }
}

// ============ final1: tile 64 x 128, BK=128, dbuf LDS ============
__global__ __launch_bounds__(256) void final1_kernel(
    const unsigned short* __restrict__ W1,
    const float* __restrict__ b1,
    const unsigned short* __restrict__ skipbf,
    unsigned short* __restrict__ t1)
{
  __shared__ unsigned short Aw[2][64 * 128];
  __shared__ unsigned short Xs[2][128 * 128];

  const int tid = threadIdx.x;
  const int lane = tid & 63;
  const int wave = tid >> 6;
  const int lm = lane & 15, qd = lane >> 4;
  const int n0 = blockIdx.x * 128;
  const int m0 = blockIdx.y * 64;
  const int wm = (wave & 1) * 32;
  const int wn = (wave >> 1) * 64;

  floatx4 acc[2][4];
  #pragma unroll
  for (int a = 0; a < 2; ++a)
    #pragma unroll
    for (int b = 0; b < 4; ++b) acc[a][b] = (floatx4){0.f, 0.f, 0.f, 0.f};

  auto stage_step = [&](int s, int b) {
    int k0 = s * 128;
    stage128<4>(&Aw[b][0], W1 + (size_t)m0 * 512 + k0, 512, tid);
    stage128<8>(&Xs[b][0], skipbf + (size_t)n0 * 512 + k0, 512, tid);
  };

  stage_step(0, 0);
  for (int s = 0; s < 4; ++s) {
    __syncthreads();
    if (s < 3) stage_step(s + 1, (s + 1) & 1);
    const unsigned short* aw = &Aw[s & 1][0];
    const unsigned short* xs = &Xs[s & 1][0];
    #pragma unroll
    for (int j = 0; j < 4; ++j) {
      int cj = j * 4 + qd;
      short8 a[2], xv[4];
      a[0] = frag128(aw, wm + lm, cj);
      a[1] = frag128(aw, wm + 16 + lm, cj);
      #pragma unroll
      for (int nt = 0; nt < 4; ++nt) xv[nt] = frag128(xs, wn + nt * 16 + lm, cj);
      #pragma unroll
      for (int mt = 0; mt < 2; ++mt)
        #pragma unroll
        for (int nt = 0; nt < 4; ++nt)
          acc[mt][nt] = MFMA_BF16(a[mt], xv[nt], acc[mt][nt]);
    }
  }

  #pragma unroll
  for (int mt = 0; mt < 2; ++mt) {
    int oc0 = m0 + wm + mt * 16 + qd * 4;
    floatx4 b4 = *(const floatx4*)&b1[oc0];
    #pragma unroll
    for (int nt = 0; nt < 4; ++nt) {
      int t = n0 + wn + nt * 16 + lm;
      ushort4v o4;
      #pragma unroll
      for (int r = 0; r < 4; ++r) {
        float v = acc[mt][nt][r] + b4[r];
        o4[r] = f2bf(v > 0.f ? v : 0.f);
      }
      *(ushort4v*)&t1[(size_t)t * 512 + oc0] = o4;
    }
  }
}

// ============ final2: one wave per t ============
__global__ __launch_bounds__(256) void final2_kernel(
    const float* __restrict__ W2, const float* __restrict__ b2,
    const unsigned short* __restrict__ t1, float* __restrict__ out)
{
  int wave = threadIdx.x >> 6, lane = threadIdx.x & 63;
  int t = blockIdx.x * 4 + wave;
  short8 v = ld8(t1 + (size_t)t * 512 + lane * 8);
  float a0 = 0.f, a1 = 0.f;
  #pragma unroll
  for (int r = 0; r < 8; ++r) {
    float f = bf2f((unsigned short)v[r]);
    a0 += W2[lane * 8 + r] * f;
    a1 += W2[512 + lane * 8 + r] * f;
  }
  #pragma unroll
  for (int off = 32; off > 0; off >>= 1) {
    a0 += __shfl_xor(a0, off, 64);
    a1 += __shfl_xor(a1, off, 64);
  }
  if (lane == 0) {
    out[t] = a0 + b2[0];
    out[TLEN + t] = a1 + b2[1];
  }
}

extern "C" void kernel_launch(void* const* d_in, const int* in_sizes, int n_in,
                              void* d_out, int out_size, void* d_ws, size_t ws_size,
                              hipStream_t stream) {
  (void)in_sizes; (void)n_in; (void)out_size; (void)ws_size;
  const float* x       = (const float*)d_in[0];
  const float* c       = (const float*)d_in[1];
  const float* front_w = (const float*)d_in[2];
  const float* front_b = (const float*)d_in[3];
  const float* filt_w  = (const float*)d_in[4];
  const float* filt_b  = (const float*)d_in[5];
  const float* gate_w  = (const float*)d_in[6];
  const float* gate_b  = (const float*)d_in[7];
  const float* cf_w    = (const float*)d_in[8];
  const float* cf_b    = (const float*)d_in[9];
  const float* cg_w    = (const float*)d_in[10];
  const float* cg_b    = (const float*)d_in[11];
  const float* res_w   = (const float*)d_in[12];
  const float* res_b   = (const float*)d_in[13];
  const float* skip_w  = (const float*)d_in[14];
  const float* skip_b  = (const float*)d_in[15];
  const float* fin1_w  = (const float*)d_in[16];
  const float* fin1_b  = (const float*)d_in[17];
  const float* fin2_w  = (const float*)d_in[18];
  const float* fin2_b  = (const float*)d_in[19];
  const float* up_w    = (const float*)d_in[20];
  const float* up_b    = (const float*)d_in[21];

  char* ws = (char*)d_ws;
  auto alloc = [&](size_t bytes) {
    char* p = ws;
    ws += (bytes + 255) & ~(size_t)255;
    return p;
  };
  unsigned short* WA     = (unsigned short*)alloc((size_t)30 * 2 * 1024 * 512 * 2);
  unsigned short* RS     = (unsigned short*)alloc((size_t)30 * 1024 * 512 * 2);
  unsigned short* CA     = (unsigned short*)alloc((size_t)30 * 1024 * 128 * 2);
  unsigned short* F1c    = (unsigned short*)alloc((size_t)512 * 512 * 2);
  float* fgb             = (float*)alloc((size_t)30 * 1024 * 4);
  float* u1              = (float*)alloc((size_t)128 * 256 * 4);
  unsigned short* cu     = (unsigned short*)alloc((size_t)TLEN * 128 * 2);
  float* hf              = (float*)alloc((size_t)TLEN * 512 * 4);
  unsigned short* hbf    = (unsigned short*)alloc((size_t)(HPADT + TLEN) * 512 * 2);
  unsigned short* obf    = (unsigned short*)alloc((size_t)TLEN * 512 * 2);
  unsigned short* skipbf = (unsigned short*)alloc((size_t)TLEN * 512 * 2);
  unsigned short* t1     = (unsigned short*)alloc((size_t)TLEN * 512 * 2);
  int* bar               = (int*)alloc(256);
  float* out             = (float*)d_out;

  // zero the left pad of hbf (tap t-d reads 0 for t < d) and the grid barrier
  hipMemsetAsync(hbf, 0, (size_t)HPADT * 512 * 2, stream);
  hipMemsetAsync(bar, 0, 256, stream);

  cast_all_kernel<<<17656, 256, 0, stream>>>(
      filt_w, gate_w, res_w, skip_w, cf_w, cg_w, fin1_w,
      filt_b, cf_b, gate_b, cg_b, WA, RS, CA, F1c, fgb);

  upsample1_kernel<<<dim3(128), 256, 0, stream>>>(c, up_w, up_b, u1);
  upsample2_kernel<<<dim3(16, 128), 256, 0, stream>>>(u1, up_w, up_b, cu);
  front_kernel<<<dim3(512, 2), 256, 0, stream>>>(x, front_w, front_b, hf, hbf);

  wavenet_main_kernel<<<256, 256, 0, stream>>>(
      WA, RS, CA, fgb, res_b, skip_b, cu, hf, hbf, obf, skipbf, bar);

  final1_kernel<<<dim3(32, 8), 256, 0, stream>>>(F1c, fin1_b, skipbf, t1);
  final2_kernel<<<1024, 256, 0, stream>>>(fin2_w, fin2_b, t1, out);
}

// Round 6
// 1314.775 us; speedup vs baseline: 3.0892x; 3.0892x over previous
//
#include <hip/hip_runtime.h>
#include <hip/hip_bf16.h>

#define TLEN 4096
#define HPADT 512
#define SQRT_HALF 0.70710678118654752f

typedef __attribute__((ext_vector_type(8))) short short8;
typedef __attribute__((ext_vector_type(4))) float floatx4;
typedef __attribute__((ext_vector_type(4))) unsigned short ushort4v;

#define MFMA_BF16(a, b, c) __builtin_amdgcn_mfma_f32_16x16x32_bf16((a), (b), (c), 0, 0, 0)

__device__ __forceinline__ float bf2f(unsigned short u) {
  union { unsigned int i; float f; } v; v.i = ((unsigned int)u) << 16; return v.f;
}
__device__ __forceinline__ unsigned short f2bf(float x) {
  union { float f; unsigned int i; } v; v.f = x;
  unsigned int r = v.i + 0x7FFFu + ((v.i >> 16) & 1u);
  return (unsigned short)(r >> 16);
}
__device__ __forceinline__ short8 ld8(const unsigned short* p) { return *(const short8*)p; }

// Stage NI*256 16B chunks of a [rows][64-elem] bf16 tile into LDS, XOR-swizzled:
// chunk c of row r lands at slot (c ^ (r&7)). dest = wave-uniform base + lane*16.
template <int NI>
__device__ __forceinline__ void stageT(unsigned short* lds, const unsigned short* src,
                                       int stride, int tid) {
  #pragma unroll
  for (int inst = 0; inst < NI; ++inst) {
    int qb = inst * 256 + (tid & 192);
    int q = qb + (tid & 63);
    int r = q >> 3;
    int c = (q & 7) ^ (r & 7);
    __builtin_amdgcn_global_load_lds(
        (const __attribute__((address_space(1))) unsigned int*)(src + (size_t)r * stride + (c << 3)),
        (__attribute__((address_space(3))) unsigned int*)(lds + qb * 8),
        16, 0, 0);
  }
}

// Read MFMA fragment from swizzled [rows][64] tile (row r, k-chunk cj in 0..7).
__device__ __forceinline__ short8 frag64(const unsigned short* lds, int r, int cj) {
  return *(const short8*)(lds + r * 64 + ((cj ^ (r & 7)) << 3));
}

// ============ merged weight pre-cast (once per call) ============
__global__ __launch_bounds__(256) void cast_all_kernel(
    const float* __restrict__ fw, const float* __restrict__ gw,
    const float* __restrict__ rw, const float* __restrict__ sw,
    const float* __restrict__ cf, const float* __restrict__ cg,
    const float* __restrict__ f1, const float* __restrict__ fb,
    const float* __restrict__ cfb, const float* __restrict__ gb,
    const float* __restrict__ cgb,
    unsigned short* __restrict__ WA, unsigned short* __restrict__ RS,
    unsigned short* __restrict__ CA, unsigned short* __restrict__ F1c,
    float* __restrict__ fgb)
{
  int b = blockIdx.x;
  if (b < 7680) {
    size_t idx = (size_t)b * 256 + threadIdx.x;
    size_t l = idx >> 16;
    int o = (int)((idx >> 7) & 511);
    int i4 = (int)(idx & 127) * 4;
    const float4* fp = (const float4*)(fw + (((l * 512 + o) * 512 + i4) * 2));
    const float4* gp = (const float4*)(gw + (((l * 512 + o) * 512 + i4) * 2));
    float4 f0 = fp[0], f1v = fp[1];
    float4 g0 = gp[0], g1 = gp[1];
    size_t base0 = ((l * 2 + 0) * 1024);
    size_t base1 = ((l * 2 + 1) * 1024);
    *(ushort4v*)&WA[(base0 + o) * 512 + i4]       = (ushort4v){f2bf(f0.x), f2bf(f0.z), f2bf(f1v.x), f2bf(f1v.z)};
    *(ushort4v*)&WA[(base1 + o) * 512 + i4]       = (ushort4v){f2bf(f0.y), f2bf(f0.w), f2bf(f1v.y), f2bf(f1v.w)};
    *(ushort4v*)&WA[(base0 + 512 + o) * 512 + i4] = (ushort4v){f2bf(g0.x), f2bf(g0.z), f2bf(g1.x), f2bf(g1.z)};
    *(ushort4v*)&WA[(base1 + 512 + o) * 512 + i4] = (ushort4v){f2bf(g0.y), f2bf(g0.w), f2bf(g1.y), f2bf(g1.w)};
  } else if (b < 15360) {
    size_t idx = (size_t)(b - 7680) * 256 + threadIdx.x;
    size_t l = idx >> 16;
    int o = (int)((idx >> 7) & 511);
    int i4 = (int)(idx & 127) * 4;
    float4 r4 = *(const float4*)(rw + ((l * 512 + o) * 512 + i4));
    float4 s4 = *(const float4*)(sw + ((l * 512 + o) * 512 + i4));
    *(ushort4v*)&RS[(l * 1024 + o) * 512 + i4]       = (ushort4v){f2bf(r4.x), f2bf(r4.y), f2bf(r4.z), f2bf(r4.w)};
    *(ushort4v*)&RS[(l * 1024 + 512 + o) * 512 + i4] = (ushort4v){f2bf(s4.x), f2bf(s4.y), f2bf(s4.z), f2bf(s4.w)};
  } else if (b < 17280) {
    size_t idx = (size_t)(b - 15360) * 256 + threadIdx.x;
    size_t l = idx >> 14;
    int o = (int)((idx >> 5) & 511);
    int i4 = (int)(idx & 31) * 4;
    float4 f4 = *(const float4*)(cf + ((l * 512 + o) * 128 + i4));
    float4 g4 = *(const float4*)(cg + ((l * 512 + o) * 128 + i4));
    *(ushort4v*)&CA[(l * 1024 + o) * 128 + i4]       = (ushort4v){f2bf(f4.x), f2bf(f4.y), f2bf(f4.z), f2bf(f4.w)};
    *(ushort4v*)&CA[(l * 1024 + 512 + o) * 128 + i4] = (ushort4v){f2bf(g4.x), f2bf(g4.y), f2bf(g4.z), f2bf(g4.w)};
  } else if (b < 17536) {
    size_t idx = (size_t)(b - 17280) * 256 + threadIdx.x;
    float4 v = *(const float4*)(f1 + idx * 4);
    *(ushort4v*)&F1c[idx * 4] = (ushort4v){f2bf(v.x), f2bf(v.y), f2bf(v.z), f2bf(v.w)};
  } else {
    int idx = (b - 17536) * 256 + threadIdx.x;
    int l = idx >> 10, r = idx & 1023;
    float v;
    if (r < 512) v = fb[l * 512 + r] + cfb[l * 512 + r];
    else         v = gb[l * 512 + r - 512] + cgb[l * 512 + r - 512];
    fgb[idx] = v;
  }
}

// ============ upsample ============

__global__ __launch_bounds__(256) void upsample1_kernel(
    const float* __restrict__ c, const float* __restrict__ up_w,
    const float* __restrict__ up_b, float* __restrict__ u1)
{
  int x = threadIdx.x;
  int h = blockIdx.x;
  const float* w = up_w;
  float acc = 0.f;
  int k1 = (23 - x) & 15;
  #pragma unroll
  for (int dk = 0; dk < 2; ++dk) {
    int kx = k1 + 16 * dk;
    int num = x + kx - 23;
    if (num >= 0) {
      int qq = num >> 4;
      if (qq < 16) {
        #pragma unroll
        for (int ky = 0; ky < 3; ++ky) {
          int hh = h + ky - 1;
          if (hh >= 0 && hh < 128)
            acc += c[hh * 16 + qq] * w[(2 - ky) * 32 + (31 - kx)];
        }
      }
    }
  }
  acc += up_b[0];
  u1[h * 256 + x] = acc > 0.f ? acc : 0.4f * acc;
}

__global__ __launch_bounds__(256) void upsample2_kernel(
    const float* __restrict__ u1, const float* __restrict__ up_w,
    const float* __restrict__ up_b, unsigned short* __restrict__ cu)
{
  int x = blockIdx.x * 256 + threadIdx.x;
  int h = blockIdx.y;
  const float* w = up_w + 96;
  float acc = 0.f;
  int k1 = (23 - x) & 15;
  #pragma unroll
  for (int dk = 0; dk < 2; ++dk) {
    int kx = k1 + 16 * dk;
    int num = x + kx - 23;
    if (num >= 0) {
      int qq = num >> 4;
      if (qq < 256) {
        #pragma unroll
        for (int ky = 0; ky < 3; ++ky) {
          int hh = h + ky - 1;
          if (hh >= 0 && hh < 128)
            acc += u1[hh * 256 + qq] * w[(2 - ky) * 32 + (31 - kx)];
        }
      }
    }
  }
  acc += up_b[1];
  acc = acc > 0.f ? acc : 0.4f * acc;
  cu[(size_t)x * 128 + h] = f2bf(acc);
}

// ============ front conv -> h[t][512] ============
__global__ __launch_bounds__(256) void front_kernel(
    const float* __restrict__ x, const float* __restrict__ fw, const float* __restrict__ fb,
    float* __restrict__ hf, unsigned short* __restrict__ hbf)
{
  __shared__ float xs[40];
  int tid = threadIdx.x;
  int o = blockIdx.y * 256 + tid;
  int t0 = blockIdx.x * 8;
  if (tid < 39) {
    int gx = t0 - 31 + tid;
    xs[tid] = (gx >= 0) ? x[gx] : 0.f;
  }
  __syncthreads();
  float w[32];
  #pragma unroll
  for (int k = 0; k < 32; ++k) w[k] = fw[o * 32 + k];
  float b = fb[o];
  #pragma unroll
  for (int j = 0; j < 8; ++j) {
    float acc = b;
    #pragma unroll
    for (int k = 0; k < 32; ++k) acc += w[k] * xs[j + k];
    acc = acc > 0.f ? acc : 0.f;
    int t = t0 + j;
    hf[(size_t)t * 512 + o] = acc;
    hbf[(size_t)(HPADT + t) * 512 + o] = f2bf(acc);
  }
}

// ============ gemm_a: dual F/G, tile 64oc x 64t, BK=64, dbuf 48 KB, 2 blk/CU ============
__global__ __launch_bounds__(256, 2) void gemm_a_kernel(
    const unsigned short* __restrict__ WA,   // [2][1024][512]
    const unsigned short* __restrict__ CA,   // [1024][128]
    const float* __restrict__ fgb,           // [1024]
    const unsigned short* __restrict__ hbf,  // [(HPADT+T)][512]
    const unsigned short* __restrict__ cu,   // [T][128]
    unsigned short* __restrict__ obf,        // [T][512]
    const int d)
{
  __shared__ unsigned short Af[2][64 * 64];
  __shared__ unsigned short Ag[2][64 * 64];
  __shared__ unsigned short Xs[2][64 * 64];

  const int tid = threadIdx.x;
  const int lane = tid & 63;
  const int wave = tid >> 6;
  const int lm = lane & 15, qd = lane >> 4;
  const int n0 = blockIdx.x * 64;
  const int m0 = blockIdx.y * 64;
  const int wm = (wave & 1) * 32;
  const int wn = (wave >> 1) * 32;

  floatx4 accF[2][2], accG[2][2];
  #pragma unroll
  for (int a = 0; a < 2; ++a)
    #pragma unroll
    for (int b = 0; b < 2; ++b) {
      accF[a][b] = (floatx4){0.f, 0.f, 0.f, 0.f};
      accG[a][b] = (floatx4){0.f, 0.f, 0.f, 0.f};
    }

  auto stage_step = [&](int s, int b) {
    if (s < 16) {
      int tap = s >> 3, k0 = (s & 7) * 64;
      const unsigned short* ab = WA + (size_t)tap * 524288;
      stageT<2>(&Af[b][0], ab + (size_t)m0 * 512 + k0, 512, tid);
      stageT<2>(&Ag[b][0], ab + (size_t)(512 + m0) * 512 + k0, 512, tid);
      stageT<2>(&Xs[b][0], hbf + (size_t)(HPADT + n0 - (tap ? 0 : d)) * 512 + k0, 512, tid);
    } else {
      int k0 = (s & 1) * 64;
      stageT<2>(&Af[b][0], CA + (size_t)m0 * 128 + k0, 128, tid);
      stageT<2>(&Ag[b][0], CA + (size_t)(512 + m0) * 128 + k0, 128, tid);
      stageT<2>(&Xs[b][0], cu + (size_t)n0 * 128 + k0, 128, tid);
    }
  };

  stage_step(0, 0);
  for (int s = 0; s < 18; ++s) {
    __syncthreads();
    if (s < 17) stage_step(s + 1, (s + 1) & 1);
    const unsigned short* af = &Af[s & 1][0];
    const unsigned short* ag = &Ag[s & 1][0];
    const unsigned short* xs = &Xs[s & 1][0];
    #pragma unroll
    for (int j = 0; j < 2; ++j) {
      int cj = qd + 4 * j;
      short8 a[2], g[2], xv[2];
      a[0] = frag64(af, wm + lm, cj);
      a[1] = frag64(af, wm + 16 + lm, cj);
      g[0] = frag64(ag, wm + lm, cj);
      g[1] = frag64(ag, wm + 16 + lm, cj);
      xv[0] = frag64(xs, wn + lm, cj);
      xv[1] = frag64(xs, wn + 16 + lm, cj);
      #pragma unroll
      for (int mt = 0; mt < 2; ++mt)
        #pragma unroll
        for (int nt = 0; nt < 2; ++nt) {
          accF[mt][nt] = MFMA_BF16(a[mt], xv[nt], accF[mt][nt]);
          accG[mt][nt] = MFMA_BF16(g[mt], xv[nt], accG[mt][nt]);
        }
    }
  }

  #pragma unroll
  for (int mt = 0; mt < 2; ++mt) {
    int oc0 = m0 + wm + mt * 16 + qd * 4;
    floatx4 fb4 = *(const floatx4*)&fgb[oc0];
    floatx4 gb4 = *(const floatx4*)&fgb[512 + oc0];
    #pragma unroll
    for (int nt = 0; nt < 2; ++nt) {
      int t = n0 + wn + nt * 16 + lm;
      ushort4v o4;
      #pragma unroll
      for (int r = 0; r < 4; ++r) {
        float f = accF[mt][nt][r] + fb4[r];
        float g = accG[mt][nt][r] + gb4[r];
        float ef = __expf(-2.f * f);
        float th = (1.f - ef) / (1.f + ef);
        float sg = 1.f / (1.f + __expf(-g));
        o4[r] = f2bf(th * sg);
      }
      *(ushort4v*)&obf[(size_t)t * 512 + oc0] = o4;
    }
  }
}

// ============ gemm_b: dual R/S, tile 64oc x 64t, BK=64, dbuf 48 KB, 2 blk/CU ============
__global__ __launch_bounds__(256, 2) void gemm_b_kernel(
    const unsigned short* __restrict__ RS,   // [1024][512]
    const float* __restrict__ rb, const float* __restrict__ sb,
    const unsigned short* __restrict__ obf,  // [T][512]
    float* __restrict__ hf, unsigned short* __restrict__ hbf,
    float* __restrict__ skip, unsigned short* __restrict__ skipbf,
    const int first, const int last)
{
  __shared__ unsigned short Ar[2][64 * 64];
  __shared__ unsigned short As_[2][64 * 64];
  __shared__ unsigned short Xs[2][64 * 64];

  const int tid = threadIdx.x;
  const int lane = tid & 63;
  const int wave = tid >> 6;
  const int lm = lane & 15, qd = lane >> 4;
  const int n0 = blockIdx.x * 64;
  const int m0 = blockIdx.y * 64;
  const int wm = (wave & 1) * 32;
  const int wn = (wave >> 1) * 32;

  floatx4 accR[2][2], accS[2][2];
  #pragma unroll
  for (int a = 0; a < 2; ++a)
    #pragma unroll
    for (int b = 0; b < 2; ++b) {
      accR[a][b] = (floatx4){0.f, 0.f, 0.f, 0.f};
      accS[a][b] = (floatx4){0.f, 0.f, 0.f, 0.f};
    }

  auto stage_step = [&](int s, int b) {
    int k0 = s * 64;
    stageT<2>(&Ar[b][0], RS + (size_t)m0 * 512 + k0, 512, tid);
    stageT<2>(&As_[b][0], RS + (size_t)(512 + m0) * 512 + k0, 512, tid);
    stageT<2>(&Xs[b][0], obf + (size_t)n0 * 512 + k0, 512, tid);
  };

  stage_step(0, 0);
  for (int s = 0; s < 8; ++s) {
    __syncthreads();
    if (s < 7) stage_step(s + 1, (s + 1) & 1);
    const unsigned short* ar = &Ar[s & 1][0];
    const unsigned short* as = &As_[s & 1][0];
    const unsigned short* xs = &Xs[s & 1][0];
    #pragma unroll
    for (int j = 0; j < 2; ++j) {
      int cj = qd + 4 * j;
      short8 a[2], g[2], xv[2];
      a[0] = frag64(ar, wm + lm, cj);
      a[1] = frag64(ar, wm + 16 + lm, cj);
      g[0] = frag64(as, wm + lm, cj);
      g[1] = frag64(as, wm + 16 + lm, cj);
      xv[0] = frag64(xs, wn + lm, cj);
      xv[1] = frag64(xs, wn + 16 + lm, cj);
      #pragma unroll
      for (int mt = 0; mt < 2; ++mt)
        #pragma unroll
        for (int nt = 0; nt < 2; ++nt) {
          accR[mt][nt] = MFMA_BF16(a[mt], xv[nt], accR[mt][nt]);
          accS[mt][nt] = MFMA_BF16(g[mt], xv[nt], accS[mt][nt]);
        }
    }
  }

  #pragma unroll
  for (int mt = 0; mt < 2; ++mt) {
    int oc0 = m0 + wm + mt * 16 + qd * 4;
    floatx4 rb4 = *(const floatx4*)&rb[oc0];
    floatx4 sb4 = *(const floatx4*)&sb[oc0];
    #pragma unroll
    for (int nt = 0; nt < 2; ++nt) {
      int t = n0 + wn + nt * 16 + lm;
      size_t base = (size_t)t * 512 + oc0;
      floatx4 h4 = *(const floatx4*)&hf[base];
      floatx4 s4;
      if (first) s4 = (floatx4){0.f, 0.f, 0.f, 0.f};
      else s4 = *(const floatx4*)&skip[base];
      ushort4v hb4;
      #pragma unroll
      for (int r = 0; r < 4; ++r) {
        float hv = (h4[r] + accR[mt][nt][r] + rb4[r]) * SQRT_HALF;
        h4[r] = hv;
        hb4[r] = f2bf(hv);
        s4[r] = s4[r] + accS[mt][nt][r] + sb4[r];
      }
      *(floatx4*)&hf[base] = h4;
      *(ushort4v*)&hbf[(size_t)(HPADT + t) * 512 + oc0] = hb4;
      *(floatx4*)&skip[base] = s4;
      if (last) {
        ushort4v sk4;
        #pragma unroll
        for (int r = 0; r < 4; ++r) sk4[r] = f2bf(s4[r] > 0.f ? s4[r] : 0.f);
        *(ushort4v*)&skipbf[base] = sk4;
      }
    }
  }
}

// ============ final1: tile 64 x 64, BK=64, dbuf 32 KB ============
__global__ __launch_bounds__(256, 2) void final1_kernel(
    const unsigned short* __restrict__ W1,       // [512][512]
    const float* __restrict__ b1,
    const unsigned short* __restrict__ skipbf,   // [T][512]
    unsigned short* __restrict__ t1)
{
  __shared__ unsigned short Aw[2][64 * 64];
  __shared__ unsigned short Xs[2][64 * 64];

  const int tid = threadIdx.x;
  const int lane = tid & 63;
  const int wave = tid >> 6;
  const int lm = lane & 15, qd = lane >> 4;
  const int n0 = blockIdx.x * 64;
  const int m0 = blockIdx.y * 64;
  const int wm = (wave & 1) * 32;
  const int wn = (wave >> 1) * 32;

  floatx4 acc[2][2];
  #pragma unroll
  for (int a = 0; a < 2; ++a)
    #pragma unroll
    for (int b = 0; b < 2; ++b) acc[a][b] = (floatx4){0.f, 0.f, 0.f, 0.f};

  auto stage_step = [&](int s, int b) {
    int k0 = s * 64;
    stageT<2>(&Aw[b][0], W1 + (size_t)m0 * 512 + k0, 512, tid);
    stageT<2>(&Xs[b][0], skipbf + (size_t)n0 * 512 + k0, 512, tid);
  };

  stage_step(0, 0);
  for (int s = 0; s < 8; ++s) {
    __syncthreads();
    if (s < 7) stage_step(s + 1, (s + 1) & 1);
    const unsigned short* aw = &Aw[s & 1][0];
    const unsigned short* xs = &Xs[s & 1][0];
    #pragma unroll
    for (int j = 0; j < 2; ++j) {
      int cj = qd + 4 * j;
      short8 a[2], xv[2];
      a[0] = frag64(aw, wm + lm, cj);
      a[1] = frag64(aw, wm + 16 + lm, cj);
      xv[0] = frag64(xs, wn + lm, cj);
      xv[1] = frag64(xs, wn + 16 + lm, cj);
      #pragma unroll
      for (int mt = 0; mt < 2; ++mt)
        #pragma unroll
        for (int nt = 0; nt < 2; ++nt)
          acc[mt][nt] = MFMA_BF16(a[mt], xv[nt], acc[mt][nt]);
    }
  }

  #pragma unroll
  for (int mt = 0; mt < 2; ++mt) {
    int oc0 = m0 + wm + mt * 16 + qd * 4;
    floatx4 b4 = *(const floatx4*)&b1[oc0];
    #pragma unroll
    for (int nt = 0; nt < 2; ++nt) {
      int t = n0 + wn + nt * 16 + lm;
      ushort4v o4;
      #pragma unroll
      for (int r = 0; r < 4; ++r) {
        float v = acc[mt][nt][r] + b4[r];
        o4[r] = f2bf(v > 0.f ? v : 0.f);
      }
      *(ushort4v*)&t1[(size_t)t * 512 + oc0] = o4;
    }
  }
}

// ============ final2: one wave per t ============
__global__ __launch_bounds__(256) void final2_kernel(
    const float* __restrict__ W2, const float* __restrict__ b2,
    const unsigned short* __restrict__ t1, float* __restrict__ out)
{
  int wave = threadIdx.x >> 6, lane = threadIdx.x & 63;
  int t = blockIdx.x * 4 + wave;
  short8 v = ld8(t1 + (size_t)t * 512 + lane * 8);
  float a0 = 0.f, a1 = 0.f;
  #pragma unroll
  for (int r = 0; r < 8; ++r) {
    float f = bf2f((unsigned short)v[r]);
    a0 += W2[lane * 8 + r] * f;
    a1 += W2[512 + lane * 8 + r] * f;
  }
  #pragma unroll
  for (int off = 32; off > 0; off >>= 1) {
    a0 += __shfl_xor(a0, off, 64);
    a1 += __shfl_xor(a1, off, 64);
  }
  if (lane == 0) {
    out[t] = a0 + b2[0];
    out[TLEN + t] = a1 + b2[1];
  }
}

extern "C" void kernel_launch(void* const* d_in, const int* in_sizes, int n_in,
                              void* d_out, int out_size, void* d_ws, size_t ws_size,
                              hipStream_t stream) {
  (void)in_sizes; (void)n_in; (void)out_size; (void)ws_size;
  const float* x       = (const float*)d_in[0];
  const float* c       = (const float*)d_in[1];
  const float* front_w = (const float*)d_in[2];
  const float* front_b = (const float*)d_in[3];
  const float* filt_w  = (const float*)d_in[4];
  const float* filt_b  = (const float*)d_in[5];
  const float* gate_w  = (const float*)d_in[6];
  const float* gate_b  = (const float*)d_in[7];
  const float* cf_w    = (const float*)d_in[8];
  const float* cf_b    = (const float*)d_in[9];
  const float* cg_w    = (const float*)d_in[10];
  const float* cg_b    = (const float*)d_in[11];
  const float* res_w   = (const float*)d_in[12];
  const float* res_b   = (const float*)d_in[13];
  const float* skip_w  = (const float*)d_in[14];
  const float* skip_b  = (const float*)d_in[15];
  const float* fin1_w  = (const float*)d_in[16];
  const float* fin1_b  = (const float*)d_in[17];
  const float* fin2_w  = (const float*)d_in[18];
  const float* fin2_b  = (const float*)d_in[19];
  const float* up_w    = (const float*)d_in[20];
  const float* up_b    = (const float*)d_in[21];

  char* ws = (char*)d_ws;
  auto alloc = [&](size_t bytes) {
    char* p = ws;
    ws += (bytes + 255) & ~(size_t)255;
    return p;
  };
  unsigned short* WA     = (unsigned short*)alloc((size_t)30 * 2 * 1024 * 512 * 2);
  unsigned short* RS     = (unsigned short*)alloc((size_t)30 * 1024 * 512 * 2);
  unsigned short* CA     = (unsigned short*)alloc((size_t)30 * 1024 * 128 * 2);
  unsigned short* F1c    = (unsigned short*)alloc((size_t)512 * 512 * 2);
  float* fgb             = (float*)alloc((size_t)30 * 1024 * 4);
  float* u1              = (float*)alloc((size_t)128 * 256 * 4);
  unsigned short* cu     = (unsigned short*)alloc((size_t)TLEN * 128 * 2);
  float* hf              = (float*)alloc((size_t)TLEN * 512 * 4);
  unsigned short* hbf    = (unsigned short*)alloc((size_t)(HPADT + TLEN) * 512 * 2);
  unsigned short* obf    = (unsigned short*)alloc((size_t)TLEN * 512 * 2);
  float* skip            = (float*)alloc((size_t)TLEN * 512 * 4);
  unsigned short* skipbf = (unsigned short*)alloc((size_t)TLEN * 512 * 2);
  unsigned short* t1     = (unsigned short*)alloc((size_t)TLEN * 512 * 2);
  float* out             = (float*)d_out;

  // zero the left pad of hbf (tap t-d reads 0 for t < d)
  hipMemsetAsync(hbf, 0, (size_t)HPADT * 512 * 2, stream);

  cast_all_kernel<<<17656, 256, 0, stream>>>(
      filt_w, gate_w, res_w, skip_w, cf_w, cg_w, fin1_w,
      filt_b, cf_b, gate_b, cg_b, WA, RS, CA, F1c, fgb);

  upsample1_kernel<<<dim3(128), 256, 0, stream>>>(c, up_w, up_b, u1);
  upsample2_kernel<<<dim3(16, 128), 256, 0, stream>>>(u1, up_w, up_b, cu);
  front_kernel<<<dim3(512, 2), 256, 0, stream>>>(x, front_w, front_b, hf, hbf);

  for (int l = 0; l < 30; ++l) {
    int d = 1 << (l % 10);
    gemm_a_kernel<<<dim3(64, 8), 256, 0, stream>>>(
        WA + (size_t)l * 2 * 524288, CA + (size_t)l * 131072,
        fgb + (size_t)l * 1024,
        hbf, cu, obf, d);
    gemm_b_kernel<<<dim3(64, 8), 256, 0, stream>>>(
        RS + (size_t)l * 524288,
        res_b + (size_t)l * 512, skip_b + (size_t)l * 512,
        obf, hf, hbf, skip, skipbf, (l == 0) ? 1 : 0, (l == 29) ? 1 : 0);
  }

  final1_kernel<<<dim3(64, 8), 256, 0, stream>>>(F1c, fin1_b, skipbf, t1);
  final2_kernel<<<1024, 256, 0, stream>>>(fin2_w, fin2_b, t1, out);
}